// Round 3
// baseline (1029.411 us; speedup 1.0000x reference)
//
#include <hip/hip_runtime.h>

#define D0 232
#define MED 1024
#define HID 256
#define TDIM 768
#define NTRAIN 4096

#define BM 128
#define BN 128
#define BK 16

// C += (gathered A1) @ W1^T [+ A2 @ W2^T], bias added once (z==0).
// Output is ALWAYS atomicAdd into a pre-zeroed C. W is (N,K) row-major.
// Split-K via blockIdx.z, chunk Kc (multiple of BK).
// 256 threads, 8x8 micro-tile, register prefetch of next K-tile.
__global__ __launch_bounds__(256) void gemm8x8(
    const float* __restrict__ A1, int lda1,
    const int* __restrict__ gather,
    const float* __restrict__ W1,
    const float* __restrict__ A2,          // optional second operand, lda = K
    const float* __restrict__ W2,
    const float* __restrict__ bias,
    float* __restrict__ C,
    int M, int N, int K, int Kc)
{
    __shared__ float As[BK][BM + 4];
    __shared__ float Bs[BK][BN + 4];

    const int tid  = threadIdx.x;
    const int tx   = tid & 15;         // 0..15 col group
    const int ty   = tid >> 4;         // 0..15 row group
    const int row0 = blockIdx.y * BM;
    const int col0 = blockIdx.x * BN;
    const int kbeg = blockIdx.z * Kc;
    const int kend = min(K, kbeg + Kc);

    const int srow = tid >> 1;         // 0..127 staging row
    const int sk   = (tid & 1) * 8;    // 0 or 8

    float acc[8][8] = {};

    for (int pass = 0; pass < 2; ++pass) {
        const float* __restrict__ A = pass ? A2 : A1;
        const float* __restrict__ W = pass ? W2 : W1;
        if (A == nullptr) break;
        const int lda = pass ? K : lda1;

        const int arow = row0 + srow;                 // M is a multiple of BM
        const int ridx = (pass == 0 && gather) ? gather[arow] : arow;
        const long abase = (long)ridx * lda;

        const int  brow   = col0 + srow;              // output column index
        const bool bvalid = brow < N;
        const long bbase  = (long)(bvalid ? brow : 0) * K;

        float4 ra0, ra1, rb0, rb1;

        auto loadTile = [&](int k0) {
            const int k = k0 + sk;
            if (k + 7 < kend) {
                ra0 = *reinterpret_cast<const float4*>(&A[abase + k]);
                ra1 = *reinterpret_cast<const float4*>(&A[abase + k + 4]);
                if (bvalid) {
                    rb0 = *reinterpret_cast<const float4*>(&W[bbase + k]);
                    rb1 = *reinterpret_cast<const float4*>(&W[bbase + k + 4]);
                } else {
                    rb0 = rb1 = make_float4(0.f, 0.f, 0.f, 0.f);
                }
            } else {
                float a[8], b[8];
                #pragma unroll
                for (int i = 0; i < 8; ++i) {
                    int kk = k + i;
                    a[i] = (kk < kend) ? A[abase + kk] : 0.0f;
                    b[i] = (bvalid && kk < kend) ? W[bbase + kk] : 0.0f;
                }
                ra0 = make_float4(a[0], a[1], a[2], a[3]);
                ra1 = make_float4(a[4], a[5], a[6], a[7]);
                rb0 = make_float4(b[0], b[1], b[2], b[3]);
                rb1 = make_float4(b[4], b[5], b[6], b[7]);
            }
        };
        auto storeTile = [&]() {
            As[sk + 0][srow] = ra0.x; As[sk + 1][srow] = ra0.y;
            As[sk + 2][srow] = ra0.z; As[sk + 3][srow] = ra0.w;
            As[sk + 4][srow] = ra1.x; As[sk + 5][srow] = ra1.y;
            As[sk + 6][srow] = ra1.z; As[sk + 7][srow] = ra1.w;
            Bs[sk + 0][srow] = rb0.x; Bs[sk + 1][srow] = rb0.y;
            Bs[sk + 2][srow] = rb0.z; Bs[sk + 3][srow] = rb0.w;
            Bs[sk + 4][srow] = rb1.x; Bs[sk + 5][srow] = rb1.y;
            Bs[sk + 6][srow] = rb1.z; Bs[sk + 7][srow] = rb1.w;
        };

        loadTile(kbeg);
        for (int k0 = kbeg; k0 < kend; k0 += BK) {
            storeTile();
            __syncthreads();
            if (k0 + BK < kend) loadTile(k0 + BK);   // prefetch next tile
            #pragma unroll
            for (int k = 0; k < BK; ++k) {
                float4 a0 = *reinterpret_cast<const float4*>(&As[k][ty * 8]);
                float4 a1 = *reinterpret_cast<const float4*>(&As[k][ty * 8 + 4]);
                float4 b0 = *reinterpret_cast<const float4*>(&Bs[k][tx * 8]);
                float4 b1 = *reinterpret_cast<const float4*>(&Bs[k][tx * 8 + 4]);
                float av[8] = {a0.x, a0.y, a0.z, a0.w, a1.x, a1.y, a1.z, a1.w};
                float bv[8] = {b0.x, b0.y, b0.z, b0.w, b1.x, b1.y, b1.z, b1.w};
                #pragma unroll
                for (int i = 0; i < 8; ++i)
                    #pragma unroll
                    for (int j = 0; j < 8; ++j)
                        acc[i][j] += av[i] * bv[j];
            }
            __syncthreads();
        }
    }

    const bool addB = (bias != nullptr) && (blockIdx.z == 0);
    #pragma unroll
    for (int i = 0; i < 8; ++i) {
        int r = row0 + ty * 8 + i;
        if (r >= M) continue;
        #pragma unroll
        for (int j = 0; j < 8; ++j) {
            int c = col0 + tx * 8 + j;
            if (c >= N) continue;
            float v = acc[i][j];
            if (addB) v += bias[c];
            atomicAdd(&C[(long)r * N + c], v);
        }
    }
}

__global__ void hist_kernel(const int* __restrict__ dst, int* __restrict__ hist, int E)
{
    int e = blockIdx.x * blockDim.x + threadIdx.x;
    if (e < E) atomicAdd(&hist[dst[e]], 1);
}

// 4096-entry exclusive scan in one 1024-thread block; also invdeg = 1/max(cnt,1)
__global__ __launch_bounds__(1024) void scan_kernel(
    const int* __restrict__ hist, int* __restrict__ row_ptr,
    float* __restrict__ invdeg, int E)
{
    __shared__ int s[1024];
    const int t = threadIdx.x;
    int4 c = reinterpret_cast<const int4*>(hist)[t];
    int local = c.x + c.y + c.z + c.w;
    s[t] = local;
    __syncthreads();
    for (int off = 1; off < 1024; off <<= 1) {
        int v = (t >= off) ? s[t - off] : 0;
        __syncthreads();
        s[t] += v;
        __syncthreads();
    }
    int base = s[t] - local;                 // exclusive
    row_ptr[4 * t + 0] = base;
    row_ptr[4 * t + 1] = base + c.x;
    row_ptr[4 * t + 2] = base + c.x + c.y;
    row_ptr[4 * t + 3] = base + c.x + c.y + c.z;
    if (t == 1023) row_ptr[4096] = E;
    invdeg[4 * t + 0] = 1.0f / fmaxf((float)c.x, 1.0f);
    invdeg[4 * t + 1] = 1.0f / fmaxf((float)c.y, 1.0f);
    invdeg[4 * t + 2] = 1.0f / fmaxf((float)c.z, 1.0f);
    invdeg[4 * t + 3] = 1.0f / fmaxf((float)c.w, 1.0f);
}

__global__ void scatter_kernel(
    const int* __restrict__ src, const int* __restrict__ dst,
    const int* __restrict__ row_ptr, int* __restrict__ cursor,
    int* __restrict__ csr, int E)
{
    int e = blockIdx.x * blockDim.x + threadIdx.x;
    if (e >= E) return;
    int d = dst[e];
    int pos = atomicAdd(&cursor[d], 1);
    csr[row_ptr[d] + pos] = src[e];
}

// One block per destination node: agg[i] = invdeg[i] * sum_{s in N(i)} x[s]
__global__ __launch_bounds__(256) void node_agg(
    const int* __restrict__ row_ptr, const int* __restrict__ csr,
    const float* __restrict__ invdeg,
    const float* __restrict__ x, float* __restrict__ agg, int D)
{
    __shared__ int nb[256];
    const int i = blockIdx.x;
    const int t = threadIdx.x;
    const int beg = row_ptr[i], end = row_ptr[i + 1];
    float a0 = 0.f, a1 = 0.f, a2 = 0.f, a3 = 0.f;
    for (int base = beg; base < end; base += 256) {
        int n = min(256, end - base);
        if (t < n) nb[t] = csr[base + t];
        __syncthreads();
        if (t < D) {
            int j = 0;
            for (; j + 3 < n; j += 4) {
                a0 += x[(long)nb[j + 0] * D + t];
                a1 += x[(long)nb[j + 1] * D + t];
                a2 += x[(long)nb[j + 2] * D + t];
                a3 += x[(long)nb[j + 3] * D + t];
            }
            for (; j < n; ++j) a0 += x[(long)nb[j] * D + t];
        }
        __syncthreads();
    }
    if (t < D) agg[(long)i * D + t] = (a0 + a1 + a2 + a3) * invdeg[i];
}

__global__ void relu_kernel(float* __restrict__ p, int n)
{
    int i = blockIdx.x * blockDim.x + threadIdx.x;
    if (i < n) p[i] = fmaxf(p[i], 0.0f);
}

// out[i,c] = sum_d x2[model_ids[i],d] * q[i,d] * cls_W[c,d] + cls_b[c]
__global__ __launch_bounds__(256) void final_head(
    const float* __restrict__ x2, const float* __restrict__ q,
    const int* __restrict__ model_ids,
    const float* __restrict__ cls_W, const float* __restrict__ cls_b,
    float* __restrict__ out, int B)
{
    int w    = (blockIdx.x * blockDim.x + threadIdx.x) >> 6;
    int lane = threadIdx.x & 63;
    if (w >= B) return;
    const float* p  = x2 + (long)model_ids[w] * D0;
    const float* qr = q + (long)w * D0;
    float s0 = 0.f, s1 = 0.f;
    for (int d = lane; d < D0; d += 64) {
        float v = p[d] * qr[d];
        s0 += v * cls_W[d];
        s1 += v * cls_W[D0 + d];
    }
    #pragma unroll
    for (int off = 32; off > 0; off >>= 1) {
        s0 += __shfl_down(s0, off);
        s1 += __shfl_down(s1, off);
    }
    if (lane == 0) {
        out[(long)w * 2 + 0] = s0 + cls_b[0];
        out[(long)w * 2 + 1] = s1 + cls_b[1];
    }
}

extern "C" void kernel_launch(void* const* d_in, const int* in_sizes, int n_in,
                              void* d_out, int out_size, void* d_ws, size_t ws_size,
                              hipStream_t stream)
{
    const float* P_weight     = (const float*)d_in[0];
    const float* model_proj_W = (const float*)d_in[1];
    const float* model_proj_b = (const float*)d_in[2];
    const float* sage1_Wl     = (const float*)d_in[3];
    const float* sage1_bl     = (const float*)d_in[4];
    const float* sage1_Wr     = (const float*)d_in[5];
    const float* sage2_Wl     = (const float*)d_in[6];
    const float* sage2_bl     = (const float*)d_in[7];
    const float* sage2_Wr     = (const float*)d_in[8];
    const float* Q_weight     = (const float*)d_in[9];
    const float* text_proj_W  = (const float*)d_in[10];
    const float* text_proj_b  = (const float*)d_in[11];
    const float* cls_W        = (const float*)d_in[12];
    const float* cls_b        = (const float*)d_in[13];
    const int*   edge_index   = (const int*)d_in[14];
    const int*   model_ids    = (const int*)d_in[15];
    const int*   prompt_ids   = (const int*)d_in[16];

    const int E = in_sizes[14] / 2;
    const int B = in_sizes[15];
    const int* src = edge_index;
    const int* dst = edge_index + E;

    // ---- workspace layout ----
    float* ws  = (float*)d_ws;
    float* x0  = ws;                                   // 4096*232
    float* h1  = x0 + (size_t)NTRAIN * D0;             // 4096*256
    float* x2  = h1 + (size_t)NTRAIN * HID;            // 4096*232
    float* q   = x2 + (size_t)NTRAIN * D0;             // B*232
    float* agg = q  + (size_t)B * D0;                  // 4096*256
    int*   ib  = (int*)(agg + (size_t)NTRAIN * HID);
    int*   hist    = ib;                               // 4096
    int*   cursor  = ib + 4096;                        // 4096
    int*   row_ptr = ib + 8192;                        // 4097 (padded)
    float* invdeg  = (float*)(ib + 12304);             // 4096
    int*   csr     = ib + 16400;                       // E

    const size_t atomicFloats = (size_t)NTRAIN * (D0 + HID + D0) + (size_t)B * D0;

    dim3 blk(256);

    // zero all atomic-accumulated GEMM outputs (x0,h1,x2,q) and CSR counters
    hipMemsetAsync(ws, 0, atomicFloats * sizeof(float), stream);
    hipMemsetAsync(ib, 0, 8192 * sizeof(int), stream);

    // ---- CSR build ----
    hist_kernel<<<(E + 255) / 256, blk, 0, stream>>>(dst, hist, E);
    scan_kernel<<<1, 1024, 0, stream>>>(hist, row_ptr, invdeg, E);
    scatter_kernel<<<(E + 255) / 256, blk, 0, stream>>>(src, dst, row_ptr, cursor, csr, E);

    // x0 = P[:4096] @ Wp^T + b   (splitK=8, Kc=128 -> 512 blocks)
    gemm8x8<<<dim3(2, NTRAIN / BM, 8), blk, 0, stream>>>(
        P_weight, MED, nullptr, model_proj_W,
        nullptr, nullptr, model_proj_b, x0, NTRAIN, D0, MED, 128);

    // layer-1 aggregation
    node_agg<<<NTRAIN, blk, 0, stream>>>(row_ptr, csr, invdeg, x0, agg, D0);

    // h1 = relu(agg @ W1l^T + b1 + x0 @ W1r^T)   (splitK=8, Kc=32 -> 512 blocks)
    gemm8x8<<<dim3(2, NTRAIN / BM, 8), blk, 0, stream>>>(
        agg, D0, nullptr, sage1_Wl,
        x0, sage1_Wr, sage1_bl, h1, NTRAIN, HID, D0, 32);
    relu_kernel<<<(NTRAIN * HID + 255) / 256, blk, 0, stream>>>(h1, NTRAIN * HID);

    // layer-2 aggregation
    node_agg<<<NTRAIN, blk, 0, stream>>>(row_ptr, csr, invdeg, h1, agg, HID);

    // x2 = agg @ W2l^T + b2 + h1 @ W2r^T   (splitK=8, Kc=32 -> 512 blocks)
    gemm8x8<<<dim3(2, NTRAIN / BM, 8), blk, 0, stream>>>(
        agg, HID, nullptr, sage2_Wl,
        h1, sage2_Wr, sage2_bl, x2, NTRAIN, D0, HID, 32);

    // q = Q[prompt_ids] @ Wt^T + b   (splitK=2, Kc=384 -> 512 blocks)
    gemm8x8<<<dim3(2, B / BM, 2), blk, 0, stream>>>(
        Q_weight, TDIM, prompt_ids, text_proj_W,
        nullptr, nullptr, text_proj_b, q, B, D0, TDIM, 384);

    // head
    final_head<<<(B * 64 + 255) / 256, blk, 0, stream>>>(
        x2, q, model_ids, cls_W, cls_b, (float*)d_out, B);
}

// Round 4
// 238.163 us; speedup vs baseline: 4.3223x; 4.3223x over previous
//
#include <hip/hip_runtime.h>

#define D0 232
#define MED 1024
#define HID 256
#define TDIM 768
#define NTRAIN 4096

#define GBM 128
#define GBN 64
#define GBK 64

typedef short bf16x8 __attribute__((ext_vector_type(8)));
typedef float f32x4  __attribute__((ext_vector_type(4)));

__device__ __forceinline__ unsigned short f2bf(float f) {
    unsigned u = __float_as_uint(f);
    unsigned r = (u + 0x7FFFu + ((u >> 16) & 1u)) >> 16;
    return (unsigned short)r;
}
__device__ __forceinline__ float bf2f(unsigned short h) {
    return __uint_as_float(((unsigned)h) << 16);
}

// C[M,N] = (gathered A1) @ W1^T [+ A2 @ W2^T] + bias, optional relu.
// W is (N,K) row-major. Split-bf16 MFMA (hi*hi + hi*lo + lo*hi), fp32 accum.
// Block tile 128x64, 4 waves (2x2), wave tile 64x32, K-step 64. Direct stores.
__global__ __launch_bounds__(256) void gemm_mfma(
    const float* __restrict__ A1, int lda1,
    const int* __restrict__ gather,
    const float* __restrict__ W1,
    const float* __restrict__ A2,          // optional second operand, lda = K
    const float* __restrict__ W2,
    const float* __restrict__ bias,
    float* __restrict__ C,
    int M, int N, int K, int doRelu)
{
    // k-panel layout: index = ((k>>3)*ROWS + row)*8 + (k&7)
    __shared__ unsigned short sAhi[GBM * GBK];
    __shared__ unsigned short sAlo[GBM * GBK];
    __shared__ unsigned short sBhi[GBN * GBK];
    __shared__ unsigned short sBlo[GBN * GBK];

    const int tid  = threadIdx.x;
    const int lane = tid & 63;
    const int wave = tid >> 6;
    const int wm   = wave >> 1;        // 0..1
    const int wn   = wave & 1;         // 0..1
    const int row0 = blockIdx.y * GBM;
    const int col0 = blockIdx.x * GBN;

    // staging coords
    const int arow = tid >> 1;          // 0..127
    const int akh  = (tid & 1) * 32;    // 0 / 32
    const int bn   = tid >> 2;          // 0..63
    const int bkh  = (tid & 3) * 16;    // 0,16,32,48

    f32x4 acc[4][2];
    #pragma unroll
    for (int m = 0; m < 4; ++m)
        #pragma unroll
        for (int j = 0; j < 2; ++j)
            acc[m][j] = (f32x4){0.f, 0.f, 0.f, 0.f};

    const int l15 = lane & 15;
    const int l4  = lane >> 4;

    for (int pass = 0; pass < 2; ++pass) {
        const float* __restrict__ A = pass ? A2 : A1;
        const float* __restrict__ W = pass ? W2 : W1;
        if (A == nullptr) break;
        const int lda = pass ? K : lda1;

        const int ridx  = (pass == 0 && gather) ? gather[row0 + arow] : (row0 + arow);
        const long long abase = (long long)ridx * lda;

        const int  bcol  = col0 + bn;
        const bool bok   = bcol < N;
        const long long bbase = (long long)(bok ? bcol : 0) * K;

        for (int k0 = 0; k0 < K; k0 += GBK) {
            // ---- stage A: 8 float4 (32 floats) per thread ----
            float4 a4[8];
            #pragma unroll
            for (int c = 0; c < 8; ++c) {
                int k = k0 + akh + c * 4;
                a4[c] = (k < K) ? *reinterpret_cast<const float4*>(&A[abase + k])
                                : make_float4(0.f, 0.f, 0.f, 0.f);
            }
            #pragma unroll
            for (int cc = 0; cc < 4; ++cc) {
                const float4 x = a4[2 * cc], y = a4[2 * cc + 1];
                float f[8] = {x.x, x.y, x.z, x.w, y.x, y.y, y.z, y.w};
                bf16x8 hi, lo;
                #pragma unroll
                for (int i = 0; i < 8; ++i) {
                    unsigned short h = f2bf(f[i]);
                    hi[i] = (short)h;
                    lo[i] = (short)f2bf(f[i] - bf2f(h));
                }
                const int slot = ((akh >> 3) + cc) * GBM + arow;
                *reinterpret_cast<bf16x8*>(&sAhi[slot * 8]) = hi;
                *reinterpret_cast<bf16x8*>(&sAlo[slot * 8]) = lo;
            }
            // ---- stage B: 4 float4 (16 floats) per thread ----
            float4 b4[4];
            #pragma unroll
            for (int c = 0; c < 4; ++c) {
                int k = k0 + bkh + c * 4;
                b4[c] = (bok && k < K) ? *reinterpret_cast<const float4*>(&W[bbase + k])
                                       : make_float4(0.f, 0.f, 0.f, 0.f);
            }
            #pragma unroll
            for (int cc = 0; cc < 2; ++cc) {
                const float4 x = b4[2 * cc], y = b4[2 * cc + 1];
                float f[8] = {x.x, x.y, x.z, x.w, y.x, y.y, y.z, y.w};
                bf16x8 hi, lo;
                #pragma unroll
                for (int i = 0; i < 8; ++i) {
                    unsigned short h = f2bf(f[i]);
                    hi[i] = (short)h;
                    lo[i] = (short)f2bf(f[i] - bf2f(h));
                }
                const int slot = ((bkh >> 3) + cc) * GBN + bn;
                *reinterpret_cast<bf16x8*>(&sBhi[slot * 8]) = hi;
                *reinterpret_cast<bf16x8*>(&sBlo[slot * 8]) = lo;
            }
            __syncthreads();

            // ---- compute: 2 k-steps of 32 ----
            #pragma unroll
            for (int ks = 0; ks < 2; ++ks) {
                const int pb = ks * 4 + l4;     // panel for this lane group
                bf16x8 ahi[4], alo[4], bhi[2], blo[2];
                #pragma unroll
                for (int m = 0; m < 4; ++m) {
                    const int slot = pb * GBM + wm * 64 + m * 16 + l15;
                    ahi[m] = *reinterpret_cast<const bf16x8*>(&sAhi[slot * 8]);
                    alo[m] = *reinterpret_cast<const bf16x8*>(&sAlo[slot * 8]);
                }
                #pragma unroll
                for (int j = 0; j < 2; ++j) {
                    const int slot = pb * GBN + wn * 32 + j * 16 + l15;
                    bhi[j] = *reinterpret_cast<const bf16x8*>(&sBhi[slot * 8]);
                    blo[j] = *reinterpret_cast<const bf16x8*>(&sBlo[slot * 8]);
                }
                #pragma unroll
                for (int m = 0; m < 4; ++m)
                    #pragma unroll
                    for (int j = 0; j < 2; ++j)
                        acc[m][j] = __builtin_amdgcn_mfma_f32_16x16x32_bf16(
                            ahi[m], bhi[j], acc[m][j], 0, 0, 0);
                #pragma unroll
                for (int m = 0; m < 4; ++m)
                    #pragma unroll
                    for (int j = 0; j < 2; ++j)
                        acc[m][j] = __builtin_amdgcn_mfma_f32_16x16x32_bf16(
                            ahi[m], blo[j], acc[m][j], 0, 0, 0);
                #pragma unroll
                for (int m = 0; m < 4; ++m)
                    #pragma unroll
                    for (int j = 0; j < 2; ++j)
                        acc[m][j] = __builtin_amdgcn_mfma_f32_16x16x32_bf16(
                            alo[m], bhi[j], acc[m][j], 0, 0, 0);
            }
            __syncthreads();
        }
    }

    // ---- epilogue: bias, relu, direct store ----
    #pragma unroll
    for (int j = 0; j < 2; ++j) {
        const int col = col0 + wn * 32 + j * 16 + l15;
        if (col >= N) continue;
        const float bv = bias[col];
        #pragma unroll
        for (int m = 0; m < 4; ++m) {
            #pragma unroll
            for (int r = 0; r < 4; ++r) {
                const int row = row0 + wm * 64 + m * 16 + l4 * 4 + r;
                float v = acc[m][j][r] + bv;
                if (doRelu) v = fmaxf(v, 0.0f);
                C[(long long)row * N + col] = v;
            }
        }
    }
}

__global__ void hist_kernel(const int* __restrict__ dst, int* __restrict__ hist, int E)
{
    int e = blockIdx.x * blockDim.x + threadIdx.x;
    if (e < E) atomicAdd(&hist[dst[e]], 1);
}

// 4096-entry exclusive scan in one 1024-thread block; also invdeg = 1/max(cnt,1)
__global__ __launch_bounds__(1024) void scan_kernel(
    const int* __restrict__ hist, int* __restrict__ row_ptr,
    float* __restrict__ invdeg, int E)
{
    __shared__ int s[1024];
    const int t = threadIdx.x;
    int4 c = reinterpret_cast<const int4*>(hist)[t];
    int local = c.x + c.y + c.z + c.w;
    s[t] = local;
    __syncthreads();
    for (int off = 1; off < 1024; off <<= 1) {
        int v = (t >= off) ? s[t - off] : 0;
        __syncthreads();
        s[t] += v;
        __syncthreads();
    }
    int base = s[t] - local;                 // exclusive
    row_ptr[4 * t + 0] = base;
    row_ptr[4 * t + 1] = base + c.x;
    row_ptr[4 * t + 2] = base + c.x + c.y;
    row_ptr[4 * t + 3] = base + c.x + c.y + c.z;
    if (t == 1023) row_ptr[4096] = E;
    invdeg[4 * t + 0] = 1.0f / fmaxf((float)c.x, 1.0f);
    invdeg[4 * t + 1] = 1.0f / fmaxf((float)c.y, 1.0f);
    invdeg[4 * t + 2] = 1.0f / fmaxf((float)c.z, 1.0f);
    invdeg[4 * t + 3] = 1.0f / fmaxf((float)c.w, 1.0f);
}

__global__ void scatter_kernel(
    const int* __restrict__ src, const int* __restrict__ dst,
    const int* __restrict__ row_ptr, int* __restrict__ cursor,
    int* __restrict__ csr, int E)
{
    int e = blockIdx.x * blockDim.x + threadIdx.x;
    if (e >= E) return;
    int d = dst[e];
    int pos = atomicAdd(&cursor[d], 1);
    csr[row_ptr[d] + pos] = src[e];
}

__device__ __forceinline__ void add4(float4& a, const float4 b) {
    a.x += b.x; a.y += b.y; a.z += b.z; a.w += b.w;
}

// One wave per destination node: agg[i] = invdeg[i] * sum_{s in N(i)} x[s]
__global__ __launch_bounds__(256) void node_agg(
    const int* __restrict__ row_ptr, const int* __restrict__ csr,
    const float* __restrict__ invdeg,
    const float* __restrict__ x, float* __restrict__ agg, int D)
{
    const int wave = threadIdx.x >> 6;
    const int lane = threadIdx.x & 63;
    const int node = blockIdx.x * 4 + wave;
    const int beg = row_ptr[node], end = row_ptr[node + 1];
    const int nf4 = D >> 2;
    const bool act = lane < nf4;
    const int fo = lane * 4;

    float4 s0 = {0,0,0,0}, s1 = {0,0,0,0}, s2 = {0,0,0,0}, s3 = {0,0,0,0};
    int j = beg;
    for (; j + 3 < end; j += 4) {
        int n0 = csr[j], n1 = csr[j + 1], n2 = csr[j + 2], n3 = csr[j + 3];
        if (act) {
            add4(s0, *reinterpret_cast<const float4*>(&x[(long long)n0 * D + fo]));
            add4(s1, *reinterpret_cast<const float4*>(&x[(long long)n1 * D + fo]));
            add4(s2, *reinterpret_cast<const float4*>(&x[(long long)n2 * D + fo]));
            add4(s3, *reinterpret_cast<const float4*>(&x[(long long)n3 * D + fo]));
        }
    }
    for (; j < end; ++j) {
        int n = csr[j];
        if (act) add4(s0, *reinterpret_cast<const float4*>(&x[(long long)n * D + fo]));
    }
    if (act) {
        const float inv = invdeg[node];
        float4 r;
        r.x = (s0.x + s1.x + s2.x + s3.x) * inv;
        r.y = (s0.y + s1.y + s2.y + s3.y) * inv;
        r.z = (s0.z + s1.z + s2.z + s3.z) * inv;
        r.w = (s0.w + s1.w + s2.w + s3.w) * inv;
        *reinterpret_cast<float4*>(&agg[(long long)node * D + fo]) = r;
    }
}

// out[i,c] = sum_d x2[model_ids[i],d] * q[i,d] * cls_W[c,d] + cls_b[c]
__global__ __launch_bounds__(256) void final_head(
    const float* __restrict__ x2, const float* __restrict__ q,
    const int* __restrict__ model_ids,
    const float* __restrict__ cls_W, const float* __restrict__ cls_b,
    float* __restrict__ out, int B)
{
    int w    = (blockIdx.x * blockDim.x + threadIdx.x) >> 6;
    int lane = threadIdx.x & 63;
    if (w >= B) return;
    const float* p  = x2 + (long long)model_ids[w] * D0;
    const float* qr = q + (long long)w * D0;
    float s0 = 0.f, s1 = 0.f;
    for (int d = lane; d < D0; d += 64) {
        float v = p[d] * qr[d];
        s0 += v * cls_W[d];
        s1 += v * cls_W[D0 + d];
    }
    #pragma unroll
    for (int off = 32; off > 0; off >>= 1) {
        s0 += __shfl_down(s0, off);
        s1 += __shfl_down(s1, off);
    }
    if (lane == 0) {
        out[(long long)w * 2 + 0] = s0 + cls_b[0];
        out[(long long)w * 2 + 1] = s1 + cls_b[1];
    }
}

extern "C" void kernel_launch(void* const* d_in, const int* in_sizes, int n_in,
                              void* d_out, int out_size, void* d_ws, size_t ws_size,
                              hipStream_t stream)
{
    const float* P_weight     = (const float*)d_in[0];
    const float* model_proj_W = (const float*)d_in[1];
    const float* model_proj_b = (const float*)d_in[2];
    const float* sage1_Wl     = (const float*)d_in[3];
    const float* sage1_bl     = (const float*)d_in[4];
    const float* sage1_Wr     = (const float*)d_in[5];
    const float* sage2_Wl     = (const float*)d_in[6];
    const float* sage2_bl     = (const float*)d_in[7];
    const float* sage2_Wr     = (const float*)d_in[8];
    const float* Q_weight     = (const float*)d_in[9];
    const float* text_proj_W  = (const float*)d_in[10];
    const float* text_proj_b  = (const float*)d_in[11];
    const float* cls_W        = (const float*)d_in[12];
    const float* cls_b        = (const float*)d_in[13];
    const int*   edge_index   = (const int*)d_in[14];
    const int*   model_ids    = (const int*)d_in[15];
    const int*   prompt_ids   = (const int*)d_in[16];

    const int E = in_sizes[14] / 2;
    const int B = in_sizes[15];
    const int* src = edge_index;
    const int* dst = edge_index + E;

    // ---- workspace layout ----
    float* ws  = (float*)d_ws;
    float* x0  = ws;                                   // 4096*232
    float* h1  = x0 + (size_t)NTRAIN * D0;             // 4096*256
    float* x2  = h1 + (size_t)NTRAIN * HID;            // 4096*232
    float* q   = x2 + (size_t)NTRAIN * D0;             // B*232
    float* agg = q  + (size_t)B * D0;                  // 4096*256
    int*   ib  = (int*)(agg + (size_t)NTRAIN * HID);
    int*   hist    = ib;                               // 4096
    int*   cursor  = ib + 4096;                        // 4096
    int*   row_ptr = ib + 8192;                        // 4097 (padded)
    float* invdeg  = (float*)(ib + 12304);             // 4096
    int*   csr     = ib + 16400;                       // E

    dim3 blk(256);

    // CSR counters only — GEMM outputs are direct-store, no pre-zero needed
    hipMemsetAsync(ib, 0, 8192 * sizeof(int), stream);

    // ---- CSR build ----
    hist_kernel<<<(E + 255) / 256, blk, 0, stream>>>(dst, hist, E);
    scan_kernel<<<1, 1024, 0, stream>>>(hist, row_ptr, invdeg, E);
    scatter_kernel<<<(E + 255) / 256, blk, 0, stream>>>(src, dst, row_ptr, cursor, csr, E);

    const int nbD0 = (D0 + GBN - 1) / GBN;   // 4

    // x0 = P[:4096] @ Wp^T + b
    gemm_mfma<<<dim3(nbD0, NTRAIN / GBM), blk, 0, stream>>>(
        P_weight, MED, nullptr, model_proj_W,
        nullptr, nullptr, model_proj_b, x0, NTRAIN, D0, MED, 0);

    // layer-1 aggregation
    node_agg<<<NTRAIN / 4, blk, 0, stream>>>(row_ptr, csr, invdeg, x0, agg, D0);

    // h1 = relu(agg @ W1l^T + b1 + x0 @ W1r^T)
    gemm_mfma<<<dim3(HID / GBN, NTRAIN / GBM), blk, 0, stream>>>(
        agg, D0, nullptr, sage1_Wl,
        x0, sage1_Wr, sage1_bl, h1, NTRAIN, HID, D0, 1);

    // layer-2 aggregation
    node_agg<<<NTRAIN / 4, blk, 0, stream>>>(row_ptr, csr, invdeg, h1, agg, HID);

    // x2 = agg @ W2l^T + b2 + h1 @ W2r^T
    gemm_mfma<<<dim3(nbD0, NTRAIN / GBM), blk, 0, stream>>>(
        agg, HID, nullptr, sage2_Wl,
        h1, sage2_Wr, sage2_bl, x2, NTRAIN, D0, HID, 0);

    // q = Q[prompt_ids] @ Wt^T + b
    gemm_mfma<<<dim3(nbD0, B / GBM), blk, 0, stream>>>(
        Q_weight, TDIM, prompt_ids, text_proj_W,
        nullptr, nullptr, text_proj_b, q, B, D0, TDIM, 0);

    // head
    final_head<<<(B * 64 + 255) / 256, blk, 0, stream>>>(
        x2, q, model_ids, cls_W, cls_b, (float*)d_out, B);
}

// Round 5
// 195.253 us; speedup vs baseline: 5.2722x; 1.2198x over previous
//
#include <hip/hip_runtime.h>

#define D0 232
#define MED 1024
#define HID 256
#define TDIM 768
#define NTRAIN 4096
#define GBK 64

typedef short bf16x8 __attribute__((ext_vector_type(8)));
typedef float f32x4  __attribute__((ext_vector_type(4)));
typedef unsigned short u16;

__device__ __forceinline__ u16 f2bf(float f) {
    unsigned u = __float_as_uint(f);
    return (u16)((u + 0x7FFFu + ((u >> 16) & 1u)) >> 16);
}
__device__ __forceinline__ float bf2f(u16 h) {
    return __uint_as_float(((unsigned)h) << 16);
}
__device__ __forceinline__ void cvt4(const float4 v, ushort4& h, ushort4& l) {
    h.x = f2bf(v.x); l.x = f2bf(v.x - bf2f(h.x));
    h.y = f2bf(v.y); l.y = f2bf(v.y - bf2f(h.y));
    h.z = f2bf(v.z); l.z = f2bf(v.z - bf2f(h.z));
    h.w = f2bf(v.w); l.w = f2bf(v.w - bf2f(h.w));
}

// ---------------- multi-segment fp32 -> bf16 hi/lo plane converter ----------------
struct Seg  { const float* src; u16* hi; u16* lo; int n4; };
struct Segs { Seg s[7]; };

__global__ __launch_bounds__(256) void conv_multi(Segs segs, int total4)
{
    int i = blockIdx.x * blockDim.x + threadIdx.x;
    const int stride = gridDim.x * blockDim.x;
    for (; i < total4; i += stride) {
        int k = i, si = 0;
        while (k >= segs.s[si].n4) { k -= segs.s[si].n4; ++si; }
        float4 v = reinterpret_cast<const float4*>(segs.s[si].src)[k];
        ushort4 h, l; cvt4(v, h, l);
        reinterpret_cast<ushort4*>(segs.s[si].hi)[k] = h;
        reinterpret_cast<ushort4*>(segs.s[si].lo)[k] = l;
    }
}

// gather rows of Q by ids, emit hi/lo planes. one block per output row.
__global__ __launch_bounds__(256) void conv_gather(
    const float* __restrict__ Q, const int* __restrict__ ids,
    u16* __restrict__ hi, u16* __restrict__ lo, int K)
{
    const int row = blockIdx.x;
    const long long sbase = (long long)ids[row] * K;
    const long long dbase = (long long)row * K;
    for (int t = threadIdx.x; t * 4 < K; t += blockDim.x) {
        float4 v = *reinterpret_cast<const float4*>(&Q[sbase + t * 4]);
        ushort4 h, l; cvt4(v, h, l);
        *reinterpret_cast<ushort4*>(&hi[dbase + t * 4]) = h;
        *reinterpret_cast<ushort4*>(&lo[dbase + t * 4]) = l;
    }
}

// ---------------- split-bf16 MFMA GEMM ----------------
// C[M,N] = A1 @ W1^T [+ A2 @ W2^T] + bias (optional relu), all operands
// pre-split bf16 hi/lo planes ([rows][K] row-major, K % 8 == 0).
// Emits fp32 C and optionally hi/lo planes of C for downstream GEMMs.
// Tile TBM x 128, 4 waves, K-step 64, register prefetch.
template<int TBM>
__global__ __launch_bounds__(256) void gemm_bf(
    const short* __restrict__ Ahi, const short* __restrict__ Alo, int lda,
    const short* __restrict__ Whi, const short* __restrict__ Wlo,
    const short* __restrict__ A2hi, const short* __restrict__ A2lo,
    const short* __restrict__ W2hi, const short* __restrict__ W2lo,
    const float* __restrict__ bias,
    float* __restrict__ Cf, u16* __restrict__ Chi, u16* __restrict__ Clo,
    int M, int N, int K, int doRelu)
{
    constexpr int TBN = 128;
    constexpr int WN  = (TBM == 64) ? 2 : 4;   // waves along N
    constexpr int WNT = TBN / WN;              // 64 or 32
    constexpr int JF  = WNT / 16;              // 4 or 2
    constexpr int ACH = TBM / 32;              // A chunks/thread/plane (2 or 1)
    constexpr int BCH = 4;                     // B chunks/thread/plane

    // k-panel layout: slot = (kc*ROWS + row)*8, kc = (k&63)>>3
    __shared__ short sAhi[8 * TBM * 8], sAlo[8 * TBM * 8];
    __shared__ short sBhi[8 * TBN * 8], sBlo[8 * TBN * 8];

    const int tid  = threadIdx.x;
    const int lane = tid & 63;
    const int wave = tid >> 6;
    const int wm   = wave / WN;
    const int wn   = wave % WN;
    const int l15  = lane & 15;
    const int l4   = lane >> 4;
    const int row0 = blockIdx.y * TBM;
    const int col0 = blockIdx.x * TBN;

    const bf16x8 Z8 = {0, 0, 0, 0, 0, 0, 0, 0};

    // staging geometry (constant across passes)
    int aRow[ACH], aK[ACH], aSlot[ACH];
    #pragma unroll
    for (int i = 0; i < ACH; ++i) {
        int cid = tid * ACH + i;
        aRow[i]  = cid >> 3;
        aK[i]    = (cid & 7) * 8;
        aSlot[i] = ((cid & 7) * TBM + aRow[i]) * 8;
    }
    int bRow[BCH], bK[BCH], bSlot[BCH];
    #pragma unroll
    for (int i = 0; i < BCH; ++i) {
        int cid = tid * BCH + i;
        bRow[i]  = cid >> 3;
        bK[i]    = (cid & 7) * 8;
        bSlot[i] = ((cid & 7) * TBN + bRow[i]) * 8;
    }

    f32x4 acc[2][JF];
    #pragma unroll
    for (int m = 0; m < 2; ++m)
        #pragma unroll
        for (int j = 0; j < JF; ++j)
            acc[m][j] = (f32x4){0.f, 0.f, 0.f, 0.f};

    for (int pass = 0; pass < 2; ++pass) {
        const short* Ah = pass ? A2hi : Ahi;
        if (Ah == nullptr) break;
        const short* Al = pass ? A2lo : Alo;
        const short* Bh = pass ? W2hi : Whi;
        const short* Bl = pass ? W2lo : Wlo;
        const int ld = pass ? K : lda;

        size_t aBase[ACH];
        #pragma unroll
        for (int i = 0; i < ACH; ++i)
            aBase[i] = (size_t)(row0 + aRow[i]) * ld;
        size_t bBase[BCH]; bool bOk[BCH];
        #pragma unroll
        for (int i = 0; i < BCH; ++i) {
            int c = col0 + bRow[i];
            bOk[i]   = c < N;
            bBase[i] = (size_t)(bOk[i] ? c : 0) * K;
        }

        bf16x8 rAh[ACH], rAl[ACH], rBh[BCH], rBl[BCH];

        auto loadT = [&](int k0) {
            #pragma unroll
            for (int i = 0; i < ACH; ++i) {
                int kg = k0 + aK[i];
                bool v = kg < K;
                rAh[i] = v ? *reinterpret_cast<const bf16x8*>(Ah + aBase[i] + kg) : Z8;
                rAl[i] = v ? *reinterpret_cast<const bf16x8*>(Al + aBase[i] + kg) : Z8;
            }
            #pragma unroll
            for (int i = 0; i < BCH; ++i) {
                int kg = k0 + bK[i];
                bool v = bOk[i] && kg < K;
                rBh[i] = v ? *reinterpret_cast<const bf16x8*>(Bh + bBase[i] + kg) : Z8;
                rBl[i] = v ? *reinterpret_cast<const bf16x8*>(Bl + bBase[i] + kg) : Z8;
            }
        };

        loadT(0);
        for (int k0 = 0; k0 < K; k0 += GBK) {
            #pragma unroll
            for (int i = 0; i < ACH; ++i) {
                *reinterpret_cast<bf16x8*>(&sAhi[aSlot[i]]) = rAh[i];
                *reinterpret_cast<bf16x8*>(&sAlo[aSlot[i]]) = rAl[i];
            }
            #pragma unroll
            for (int i = 0; i < BCH; ++i) {
                *reinterpret_cast<bf16x8*>(&sBhi[bSlot[i]]) = rBh[i];
                *reinterpret_cast<bf16x8*>(&sBlo[bSlot[i]]) = rBl[i];
            }
            __syncthreads();
            if (k0 + GBK < K) loadT(k0 + GBK);   // prefetch next tile

            #pragma unroll
            for (int ks = 0; ks < 2; ++ks) {
                const int pb = ks * 4 + l4;
                bf16x8 ah[2], al[2], bh[JF], bl[JF];
                #pragma unroll
                for (int m = 0; m < 2; ++m) {
                    int sl = (pb * TBM + wm * 32 + m * 16 + l15) * 8;
                    ah[m] = *reinterpret_cast<const bf16x8*>(&sAhi[sl]);
                    al[m] = *reinterpret_cast<const bf16x8*>(&sAlo[sl]);
                }
                #pragma unroll
                for (int j = 0; j < JF; ++j) {
                    int sl = (pb * TBN + wn * WNT + j * 16 + l15) * 8;
                    bh[j] = *reinterpret_cast<const bf16x8*>(&sBhi[sl]);
                    bl[j] = *reinterpret_cast<const bf16x8*>(&sBlo[sl]);
                }
                #pragma unroll
                for (int m = 0; m < 2; ++m)
                    #pragma unroll
                    for (int j = 0; j < JF; ++j)
                        acc[m][j] = __builtin_amdgcn_mfma_f32_16x16x32_bf16(
                            ah[m], bh[j], acc[m][j], 0, 0, 0);
                #pragma unroll
                for (int m = 0; m < 2; ++m)
                    #pragma unroll
                    for (int j = 0; j < JF; ++j)
                        acc[m][j] = __builtin_amdgcn_mfma_f32_16x16x32_bf16(
                            ah[m], bl[j], acc[m][j], 0, 0, 0);
                #pragma unroll
                for (int m = 0; m < 2; ++m)
                    #pragma unroll
                    for (int j = 0; j < JF; ++j)
                        acc[m][j] = __builtin_amdgcn_mfma_f32_16x16x32_bf16(
                            al[m], bh[j], acc[m][j], 0, 0, 0);
            }
            __syncthreads();
        }
    }

    // epilogue: bias, relu, fp32 store, optional hi/lo plane store
    #pragma unroll
    for (int j = 0; j < JF; ++j) {
        const int col = col0 + wn * WNT + j * 16 + l15;
        if (col >= N) continue;
        const float bv = bias[col];
        #pragma unroll
        for (int m = 0; m < 2; ++m) {
            #pragma unroll
            for (int r = 0; r < 4; ++r) {
                const int row = row0 + wm * 32 + m * 16 + l4 * 4 + r;
                float v = acc[m][j][r] + bv;
                if (doRelu) v = fmaxf(v, 0.0f);
                const size_t idx = (size_t)row * N + col;
                Cf[idx] = v;
                if (Chi) {
                    u16 h = f2bf(v);
                    Chi[idx] = h;
                    Clo[idx] = f2bf(v - bf2f(h));
                }
            }
        }
    }
}

// ---------------- CSR build ----------------
__global__ void hist_kernel(const int* __restrict__ dst, int* __restrict__ hist, int E)
{
    int e = blockIdx.x * blockDim.x + threadIdx.x;
    if (e < E) atomicAdd(&hist[dst[e]], 1);
}

__global__ __launch_bounds__(1024) void scan_kernel(
    const int* __restrict__ hist, int* __restrict__ row_ptr,
    float* __restrict__ invdeg, int E)
{
    __shared__ int s[1024];
    const int t = threadIdx.x;
    int4 c = reinterpret_cast<const int4*>(hist)[t];
    int local = c.x + c.y + c.z + c.w;
    s[t] = local;
    __syncthreads();
    for (int off = 1; off < 1024; off <<= 1) {
        int v = (t >= off) ? s[t - off] : 0;
        __syncthreads();
        s[t] += v;
        __syncthreads();
    }
    int base = s[t] - local;
    row_ptr[4 * t + 0] = base;
    row_ptr[4 * t + 1] = base + c.x;
    row_ptr[4 * t + 2] = base + c.x + c.y;
    row_ptr[4 * t + 3] = base + c.x + c.y + c.z;
    if (t == 1023) row_ptr[4096] = E;
    invdeg[4 * t + 0] = 1.0f / fmaxf((float)c.x, 1.0f);
    invdeg[4 * t + 1] = 1.0f / fmaxf((float)c.y, 1.0f);
    invdeg[4 * t + 2] = 1.0f / fmaxf((float)c.z, 1.0f);
    invdeg[4 * t + 3] = 1.0f / fmaxf((float)c.w, 1.0f);
}

__global__ void scatter_kernel(
    const int* __restrict__ src, const int* __restrict__ dst,
    const int* __restrict__ row_ptr, int* __restrict__ cursor,
    int* __restrict__ csr, int E)
{
    int e = blockIdx.x * blockDim.x + threadIdx.x;
    if (e >= E) return;
    int d = dst[e];
    int pos = atomicAdd(&cursor[d], 1);
    csr[row_ptr[d] + pos] = src[e];
}

__device__ __forceinline__ void add4(float4& a, const float4 b) {
    a.x += b.x; a.y += b.y; a.z += b.z; a.w += b.w;
}

// one wave per node: mean of neighbor rows, emitted as hi/lo bf16 planes
__global__ __launch_bounds__(256) void node_agg(
    const int* __restrict__ row_ptr, const int* __restrict__ csr,
    const float* __restrict__ invdeg,
    const float* __restrict__ x, u16* __restrict__ agghi, u16* __restrict__ agglo, int D)
{
    const int wave = threadIdx.x >> 6;
    const int lane = threadIdx.x & 63;
    const int node = blockIdx.x * 4 + wave;
    const int beg = row_ptr[node], end = row_ptr[node + 1];
    const bool act = lane < (D >> 2);
    const int fo = lane * 4;

    float4 s0 = {0,0,0,0}, s1 = {0,0,0,0}, s2 = {0,0,0,0}, s3 = {0,0,0,0};
    int j = beg;
    for (; j + 3 < end; j += 4) {
        int n0 = csr[j], n1 = csr[j + 1], n2 = csr[j + 2], n3 = csr[j + 3];
        if (act) {
            add4(s0, *reinterpret_cast<const float4*>(&x[(long long)n0 * D + fo]));
            add4(s1, *reinterpret_cast<const float4*>(&x[(long long)n1 * D + fo]));
            add4(s2, *reinterpret_cast<const float4*>(&x[(long long)n2 * D + fo]));
            add4(s3, *reinterpret_cast<const float4*>(&x[(long long)n3 * D + fo]));
        }
    }
    for (; j < end; ++j) {
        int n = csr[j];
        if (act) add4(s0, *reinterpret_cast<const float4*>(&x[(long long)n * D + fo]));
    }
    if (act) {
        const float inv = invdeg[node];
        float4 r;
        r.x = (s0.x + s1.x + s2.x + s3.x) * inv;
        r.y = (s0.y + s1.y + s2.y + s3.y) * inv;
        r.z = (s0.z + s1.z + s2.z + s3.z) * inv;
        r.w = (s0.w + s1.w + s2.w + s3.w) * inv;
        ushort4 h, l; cvt4(r, h, l);
        *reinterpret_cast<ushort4*>(&agghi[(size_t)node * D + fo]) = h;
        *reinterpret_cast<ushort4*>(&agglo[(size_t)node * D + fo]) = l;
    }
}

// out[i,c] = sum_d x2[model_ids[i],d] * q[i,d] * cls_W[c,d] + cls_b[c]
__global__ __launch_bounds__(256) void final_head(
    const float* __restrict__ x2, const float* __restrict__ q,
    const int* __restrict__ model_ids,
    const float* __restrict__ cls_W, const float* __restrict__ cls_b,
    float* __restrict__ out, int B)
{
    int w    = (blockIdx.x * blockDim.x + threadIdx.x) >> 6;
    int lane = threadIdx.x & 63;
    if (w >= B) return;
    const float* p  = x2 + (long long)model_ids[w] * D0;
    const float* qr = q + (long long)w * D0;
    float s0 = 0.f, s1 = 0.f;
    for (int d = lane; d < D0; d += 64) {
        float v = p[d] * qr[d];
        s0 += v * cls_W[d];
        s1 += v * cls_W[D0 + d];
    }
    #pragma unroll
    for (int off = 32; off > 0; off >>= 1) {
        s0 += __shfl_down(s0, off);
        s1 += __shfl_down(s1, off);
    }
    if (lane == 0) {
        out[(long long)w * 2 + 0] = s0 + cls_b[0];
        out[(long long)w * 2 + 1] = s1 + cls_b[1];
    }
}

extern "C" void kernel_launch(void* const* d_in, const int* in_sizes, int n_in,
                              void* d_out, int out_size, void* d_ws, size_t ws_size,
                              hipStream_t stream)
{
    const float* P_weight     = (const float*)d_in[0];
    const float* model_proj_W = (const float*)d_in[1];
    const float* model_proj_b = (const float*)d_in[2];
    const float* sage1_Wl     = (const float*)d_in[3];
    const float* sage1_bl     = (const float*)d_in[4];
    const float* sage1_Wr     = (const float*)d_in[5];
    const float* sage2_Wl     = (const float*)d_in[6];
    const float* sage2_bl     = (const float*)d_in[7];
    const float* sage2_Wr     = (const float*)d_in[8];
    const float* Q_weight     = (const float*)d_in[9];
    const float* text_proj_W  = (const float*)d_in[10];
    const float* text_proj_b  = (const float*)d_in[11];
    const float* cls_W        = (const float*)d_in[12];
    const float* cls_b        = (const float*)d_in[13];
    const int*   edge_index   = (const int*)d_in[14];
    const int*   model_ids    = (const int*)d_in[15];
    const int*   prompt_ids   = (const int*)d_in[16];

    const int E = in_sizes[14] / 2;
    const int B = in_sizes[15];
    const int* srcE = edge_index;
    const int* dstE = edge_index + E;

    // ---- workspace layout ----
    const size_t nX0 = (size_t)NTRAIN * D0;     // 950272
    const size_t nH1 = (size_t)NTRAIN * HID;    // 1048576
    const size_t nQ  = (size_t)B * D0;          // 3801088
    const size_t nP  = (size_t)NTRAIN * MED;    // 4194304
    const size_t nQg = (size_t)B * TDIM;        // 12582912
    const size_t nWp = (size_t)D0 * MED;        // 237568
    const size_t nWs = (size_t)HID * D0;        // 59392 (sage1 l/r, sage2 l/r all same count)
    const size_t nWt = (size_t)D0 * TDIM;       // 178176
    const size_t nWAll = nWp + 4 * nWs + nWt;   // 653312

    float* fp = (float*)d_ws;
    float* x0f = fp;            fp += nX0;
    float* h1f = fp;            fp += nH1;
    float* x2f = fp;            fp += nX0;
    float* qf  = fp;            fp += nQ;
    u16* sp = (u16*)fp;
    u16* x0h = sp;              sp += nX0;
    u16* x0l = sp;              sp += nX0;
    u16* h1h = sp;              sp += nH1;
    u16* h1l = sp;              sp += nH1;
    u16* agh = sp;              sp += nH1;    // max(D0,HID) rows
    u16* agl = sp;              sp += nH1;
    u16* Ph  = sp;              sp += nP;
    u16* Pl  = sp;              sp += nP;
    u16* Qh  = sp;              sp += nQg;
    u16* Ql  = sp;              sp += nQg;
    u16* Wh  = sp;              sp += nWAll;
    u16* Wl  = sp;              sp += nWAll;
    int* ib  = (int*)sp;
    int*   hist    = ib;
    int*   cursor  = ib + 4096;
    int*   row_ptr = ib + 8192;              // 4097, padded
    float* invdeg  = (float*)(ib + 12304);
    int*   csr     = ib + 16400;

    // weight plane offsets (in shorts)
    u16 *Wph = Wh,            *Wpl = Wl;
    u16 *W1lh = Wh + nWp,     *W1ll = Wl + nWp;
    u16 *W1rh = W1lh + nWs,   *W1rl = W1ll + nWs;
    u16 *W2lh = W1rh + nWs,   *W2ll = W1rl + nWs;
    u16 *W2rh = W2lh + nWs,   *W2rl = W2ll + nWs;
    u16 *Wth  = W2rh + nWs,   *Wtl  = W2rl + nWs;

    dim3 blk(256);

    hipMemsetAsync(ib, 0, 8192 * sizeof(int), stream);

    // CSR build
    hist_kernel<<<(E + 255) / 256, blk, 0, stream>>>(dstE, hist, E);
    scan_kernel<<<1, 1024, 0, stream>>>(hist, row_ptr, invdeg, E);
    scatter_kernel<<<(E + 255) / 256, blk, 0, stream>>>(srcE, dstE, row_ptr, cursor, csr, E);

    // convert P[:4096] + all weights to hi/lo planes (one kernel)
    Segs segs;
    segs.s[0] = {P_weight,     Ph,   Pl,   (int)(nP  / 4)};
    segs.s[1] = {model_proj_W, Wph,  Wpl,  (int)(nWp / 4)};
    segs.s[2] = {sage1_Wl,     W1lh, W1ll, (int)(nWs / 4)};
    segs.s[3] = {sage1_Wr,     W1rh, W1rl, (int)(nWs / 4)};
    segs.s[4] = {sage2_Wl,     W2lh, W2ll, (int)(nWs / 4)};
    segs.s[5] = {sage2_Wr,     W2rh, W2rl, (int)(nWs / 4)};
    segs.s[6] = {text_proj_W,  Wth,  Wtl,  (int)(nWt / 4)};
    int total4 = (int)((nP + nWAll) / 4);
    conv_multi<<<2048, blk, 0, stream>>>(segs, total4);

    // gather+convert Q rows
    conv_gather<<<B, blk, 0, stream>>>(Q_weight, prompt_ids, Qh, Ql, TDIM);

    // x0 = P @ Wp^T + b          (also emits x0 hi/lo)
    gemm_bf<32><<<dim3(2, NTRAIN / 32), blk, 0, stream>>>(
        (const short*)Ph, (const short*)Pl, MED,
        (const short*)Wph, (const short*)Wpl,
        nullptr, nullptr, nullptr, nullptr,
        model_proj_b, x0f, x0h, x0l, NTRAIN, D0, MED, 0);

    // layer-1 aggregation -> hi/lo planes
    node_agg<<<NTRAIN / 4, blk, 0, stream>>>(row_ptr, csr, invdeg, x0f, agh, agl, D0);

    // h1 = relu(agg @ W1l^T + b1 + x0 @ W1r^T)   (emits h1 hi/lo)
    gemm_bf<32><<<dim3(2, NTRAIN / 32), blk, 0, stream>>>(
        (const short*)agh, (const short*)agl, D0,
        (const short*)W1lh, (const short*)W1ll,
        (const short*)x0h, (const short*)x0l,
        (const short*)W1rh, (const short*)W1rl,
        sage1_bl, h1f, h1h, h1l, NTRAIN, HID, D0, 1);

    // layer-2 aggregation
    node_agg<<<NTRAIN / 4, blk, 0, stream>>>(row_ptr, csr, invdeg, h1f, agh, agl, HID);

    // x2 = agg @ W2l^T + b2 + h1 @ W2r^T   (fp32 only)
    gemm_bf<32><<<dim3(2, NTRAIN / 32), blk, 0, stream>>>(
        (const short*)agh, (const short*)agl, HID,
        (const short*)W2lh, (const short*)W2ll,
        (const short*)h1h, (const short*)h1l,
        (const short*)W2rh, (const short*)W2rl,
        sage2_bl, x2f, nullptr, nullptr, NTRAIN, D0, HID, 0);

    // q = Qg @ Wt^T + b   (fp32 only)
    gemm_bf<64><<<dim3(2, B / 64), blk, 0, stream>>>(
        (const short*)Qh, (const short*)Ql, TDIM,
        (const short*)Wth, (const short*)Wtl,
        nullptr, nullptr, nullptr, nullptr,
        text_proj_b, qf, nullptr, nullptr, B, D0, TDIM, 0);

    // head
    final_head<<<(B * 64 + 255) / 256, blk, 0, stream>>>(
        x2f, qf, model_ids, cls_W, cls_b, (float*)d_out, B);
}

// Round 6
// 167.780 us; speedup vs baseline: 6.1355x; 1.1637x over previous
//
#include <hip/hip_runtime.h>

#define D0 232
#define MED 1024
#define HID 256
#define TDIM 768
#define NTRAIN 4096

typedef short bf16x8 __attribute__((ext_vector_type(8)));
typedef float f32x4  __attribute__((ext_vector_type(4)));
typedef unsigned short u16;

__device__ __forceinline__ u16 f2bf(float f) {
    unsigned u = __float_as_uint(f);
    return (u16)((u + 0x7FFFu + ((u >> 16) & 1u)) >> 16);
}
__device__ __forceinline__ float bf2f(u16 h) {
    return __uint_as_float(((unsigned)h) << 16);
}
__device__ __forceinline__ void cvt8(const float4& a0, const float4& a1,
                                     bf16x8& h, bf16x8& l) {
    float f[8] = {a0.x, a0.y, a0.z, a0.w, a1.x, a1.y, a1.z, a1.w};
    #pragma unroll
    for (int i = 0; i < 8; ++i) {
        u16 hh = f2bf(f[i]);
        h[i] = (short)hh;
        l[i] = (short)f2bf(f[i] - bf2f(hh));
    }
}

// XOR row swizzle: makes both ds_write_b128 (kc varies per lane-group) and
// ds_read_b128 (row varies per lane) 2-way on 32 banks (free).
#define SROW(r, k) ((((r) ^ (k)) & 7) | ((r) & ~7))

// ---------------- node GEMM: C = A1@W1^T [+ A2@W2^T] + bias ----------------
// A1 fp32 [M][K] (split to bf16 hi/lo in staging); A2/W pre-split planes.
// Tile 32x128, 4 waves (all along N), K-step 64. Direct stores.
template<int RELU, int EMIT>
__global__ __launch_bounds__(256) void gemm_node(
    const float* __restrict__ A1,
    const short* __restrict__ Whi, const short* __restrict__ Wlo,
    const short* __restrict__ A2hi, const short* __restrict__ A2lo,
    const short* __restrict__ W2hi, const short* __restrict__ W2lo,
    const float* __restrict__ bias,
    float* __restrict__ Cf, u16* __restrict__ Chi, u16* __restrict__ Clo,
    int M, int N, int K)
{
    constexpr int TBM = 32, TBN = 128;
    __shared__ short sAh[8 * TBM * 8], sAl[8 * TBM * 8];
    __shared__ short sBh[8 * TBN * 8], sBl[8 * TBN * 8];

    const int tid  = threadIdx.x;
    const int lane = tid & 63;
    const int wn   = tid >> 6;      // wave 0..3, split along N
    const int l15  = lane & 15;
    const int l4   = lane >> 4;
    const int row0 = blockIdx.y * TBM;
    const int col0 = blockIdx.x * TBN;

    const int aRow  = tid >> 3;     // 0..31
    const int aKc   = tid & 7;
    const int aSlot = (aKc * TBM + SROW(aRow, aKc)) * 8;

    int bKcA[4], bSlot[4], bRowL[4];
    #pragma unroll
    for (int i = 0; i < 4; ++i) {
        int cid  = tid * 4 + i;
        bRowL[i] = cid >> 3;        // 0..127
        bKcA[i]  = cid & 7;
        bSlot[i] = (bKcA[i] * TBN + SROW(bRowL[i], bKcA[i])) * 8;
    }

    const bf16x8 Z8 = {0, 0, 0, 0, 0, 0, 0, 0};
    f32x4 acc[2][2];
    #pragma unroll
    for (int m = 0; m < 2; ++m)
        #pragma unroll
        for (int j = 0; j < 2; ++j)
            acc[m][j] = (f32x4){0.f, 0.f, 0.f, 0.f};

    for (int pass = 0; pass < 2; ++pass) {
        if (pass && A2hi == nullptr) break;
        const short* Bh = pass ? W2hi : Whi;
        const short* Bl = pass ? W2lo : Wlo;

        const size_t aBase = (size_t)(row0 + aRow) * K;
        size_t bBase[4]; bool bOk[4];
        #pragma unroll
        for (int i = 0; i < 4; ++i) {
            int c = col0 + bRowL[i];
            bOk[i]   = c < N;
            bBase[i] = (size_t)(bOk[i] ? c : 0) * K;
        }

        float4 a0, a1;
        bf16x8 pAh, pAl, rBh[4], rBl[4];

        auto loadT = [&](int k0) {
            int gk = k0 + aKc * 8;
            bool av = gk < K;              // K % 8 == 0 always
            if (pass == 0) {
                a0 = av ? *reinterpret_cast<const float4*>(A1 + aBase + gk)
                        : make_float4(0.f, 0.f, 0.f, 0.f);
                a1 = av ? *reinterpret_cast<const float4*>(A1 + aBase + gk + 4)
                        : make_float4(0.f, 0.f, 0.f, 0.f);
            } else {
                pAh = av ? *reinterpret_cast<const bf16x8*>(A2hi + aBase + gk) : Z8;
                pAl = av ? *reinterpret_cast<const bf16x8*>(A2lo + aBase + gk) : Z8;
            }
            #pragma unroll
            for (int i = 0; i < 4; ++i) {
                int k = k0 + bKcA[i] * 8;
                bool v = bOk[i] && k < K;
                rBh[i] = v ? *reinterpret_cast<const bf16x8*>(Bh + bBase[i] + k) : Z8;
                rBl[i] = v ? *reinterpret_cast<const bf16x8*>(Bl + bBase[i] + k) : Z8;
            }
        };
        auto storeT = [&]() {
            if (pass == 0) {
                bf16x8 h, l; cvt8(a0, a1, h, l);
                *reinterpret_cast<bf16x8*>(sAh + aSlot) = h;
                *reinterpret_cast<bf16x8*>(sAl + aSlot) = l;
            } else {
                *reinterpret_cast<bf16x8*>(sAh + aSlot) = pAh;
                *reinterpret_cast<bf16x8*>(sAl + aSlot) = pAl;
            }
            #pragma unroll
            for (int i = 0; i < 4; ++i) {
                *reinterpret_cast<bf16x8*>(sBh + bSlot[i]) = rBh[i];
                *reinterpret_cast<bf16x8*>(sBl + bSlot[i]) = rBl[i];
            }
        };

        loadT(0);
        for (int k0 = 0; k0 < K; k0 += 64) {
            storeT();
            __syncthreads();
            if (k0 + 64 < K) loadT(k0 + 64);
            #pragma unroll
            for (int ks = 0; ks < 2; ++ks) {
                const int pb = ks * 4 + l4;
                bf16x8 ah[2], al[2], bh[2], bl[2];
                #pragma unroll
                for (int m = 0; m < 2; ++m) {
                    int r  = m * 16 + l15;
                    int sl = (pb * TBM + SROW(r, pb)) * 8;
                    ah[m] = *reinterpret_cast<const bf16x8*>(sAh + sl);
                    al[m] = *reinterpret_cast<const bf16x8*>(sAl + sl);
                }
                #pragma unroll
                for (int j = 0; j < 2; ++j) {
                    int r  = wn * 32 + j * 16 + l15;
                    int sl = (pb * TBN + SROW(r, pb)) * 8;
                    bh[j] = *reinterpret_cast<const bf16x8*>(sBh + sl);
                    bl[j] = *reinterpret_cast<const bf16x8*>(sBl + sl);
                }
                #pragma unroll
                for (int m = 0; m < 2; ++m)
                    #pragma unroll
                    for (int j = 0; j < 2; ++j)
                        acc[m][j] = __builtin_amdgcn_mfma_f32_16x16x32_bf16(
                            ah[m], bh[j], acc[m][j], 0, 0, 0);
                #pragma unroll
                for (int m = 0; m < 2; ++m)
                    #pragma unroll
                    for (int j = 0; j < 2; ++j)
                        acc[m][j] = __builtin_amdgcn_mfma_f32_16x16x32_bf16(
                            ah[m], bl[j], acc[m][j], 0, 0, 0);
                #pragma unroll
                for (int m = 0; m < 2; ++m)
                    #pragma unroll
                    for (int j = 0; j < 2; ++j)
                        acc[m][j] = __builtin_amdgcn_mfma_f32_16x16x32_bf16(
                            al[m], bh[j], acc[m][j], 0, 0, 0);
            }
            __syncthreads();
        }
    }

    #pragma unroll
    for (int j = 0; j < 2; ++j) {
        int col = col0 + wn * 32 + j * 16 + l15;
        if (col >= N) continue;
        float bv = bias[col];
        #pragma unroll
        for (int m = 0; m < 2; ++m) {
            #pragma unroll
            for (int r = 0; r < 4; ++r) {
                int row = row0 + m * 16 + l4 * 4 + r;
                float v = acc[m][j][r] + bv;
                if (RELU) v = fmaxf(v, 0.0f);
                size_t idx = (size_t)row * N + col;
                Cf[idx] = v;
                if (EMIT) {
                    u16 h = f2bf(v);
                    Chi[idx] = h;
                    Clo[idx] = f2bf(v - bf2f(h));
                }
            }
        }
    }
}

// ------- fused q-GEMM + head: out = (x2[mid] * (Q[pid]@Wt^T + b)) @ clsW^T + cls_b -------
// Tile 64x256 (all of N=232 in one block), 8 waves (2M x 4N), K=768.
__global__ __launch_bounds__(512) void gemm_q_head(
    const float* __restrict__ Q,
    const int* __restrict__ prompt_ids,
    const short* __restrict__ Whi, const short* __restrict__ Wlo,
    const float* __restrict__ bias,
    const float* __restrict__ x2f,
    const int* __restrict__ model_ids,
    const float* __restrict__ cls_W, const float* __restrict__ cls_b,
    float* __restrict__ out)
{
    constexpr int TBM = 64, TBN = 256, K = TDIM, N = D0;
    __shared__ short sAh[8 * TBM * 8], sAl[8 * TBM * 8];
    __shared__ short sBh[8 * TBN * 8], sBl[8 * TBN * 8];
    __shared__ float hacc[TBM][2];

    const int tid  = threadIdx.x;
    const int lane = tid & 63;
    const int wave = tid >> 6;
    const int wm   = wave >> 2;     // 0..1
    const int wn   = wave & 3;      // 0..3
    const int l15  = lane & 15;
    const int l4   = lane >> 4;
    const int row0 = blockIdx.x * TBM;

    const int aRow  = tid >> 3;     // 0..63
    const int aKc   = tid & 7;
    const int aSlot = (aKc * TBM + SROW(aRow, aKc)) * 8;
    const size_t aBase = (size_t)prompt_ids[row0 + aRow] * K;

    int bKcA[4], bSlot[4]; bool bOk[4]; size_t bBase[4];
    #pragma unroll
    for (int i = 0; i < 4; ++i) {
        int cid   = tid * 4 + i;
        int br    = cid >> 3;       // 0..255
        bKcA[i]   = cid & 7;
        bSlot[i]  = (bKcA[i] * TBN + SROW(br, bKcA[i])) * 8;
        bOk[i]    = br < N;
        bBase[i]  = (size_t)(bOk[i] ? br : 0) * K;
    }

    const bf16x8 Z8 = {0, 0, 0, 0, 0, 0, 0, 0};
    f32x4 acc[2][4];
    #pragma unroll
    for (int m = 0; m < 2; ++m)
        #pragma unroll
        for (int j = 0; j < 4; ++j)
            acc[m][j] = (f32x4){0.f, 0.f, 0.f, 0.f};

    float4 a0, a1;
    bf16x8 rBh[4], rBl[4];

    auto loadT = [&](int k0) {
        int gk = k0 + aKc * 8;       // always < K (K%64==0)
        a0 = *reinterpret_cast<const float4*>(Q + aBase + gk);
        a1 = *reinterpret_cast<const float4*>(Q + aBase + gk + 4);
        #pragma unroll
        for (int i = 0; i < 4; ++i) {
            int k = k0 + bKcA[i] * 8;
            rBh[i] = bOk[i] ? *reinterpret_cast<const bf16x8*>(Whi + bBase[i] + k) : Z8;
            rBl[i] = bOk[i] ? *reinterpret_cast<const bf16x8*>(Wlo + bBase[i] + k) : Z8;
        }
    };
    auto storeT = [&]() {
        bf16x8 h, l; cvt8(a0, a1, h, l);
        *reinterpret_cast<bf16x8*>(sAh + aSlot) = h;
        *reinterpret_cast<bf16x8*>(sAl + aSlot) = l;
        #pragma unroll
        for (int i = 0; i < 4; ++i) {
            *reinterpret_cast<bf16x8*>(sBh + bSlot[i]) = rBh[i];
            *reinterpret_cast<bf16x8*>(sBl + bSlot[i]) = rBl[i];
        }
    };

    loadT(0);
    for (int k0 = 0; k0 < K; k0 += 64) {
        storeT();
        __syncthreads();
        if (k0 + 64 < K) loadT(k0 + 64);
        #pragma unroll
        for (int ks = 0; ks < 2; ++ks) {
            const int pb = ks * 4 + l4;
            bf16x8 ah[2], al[2], bh[4], bl[4];
            #pragma unroll
            for (int m = 0; m < 2; ++m) {
                int r  = wm * 32 + m * 16 + l15;
                int sl = (pb * TBM + SROW(r, pb)) * 8;
                ah[m] = *reinterpret_cast<const bf16x8*>(sAh + sl);
                al[m] = *reinterpret_cast<const bf16x8*>(sAl + sl);
            }
            #pragma unroll
            for (int j = 0; j < 4; ++j) {
                int r  = wn * 64 + j * 16 + l15;
                int sl = (pb * TBN + SROW(r, pb)) * 8;
                bh[j] = *reinterpret_cast<const bf16x8*>(sBh + sl);
                bl[j] = *reinterpret_cast<const bf16x8*>(sBl + sl);
            }
            #pragma unroll
            for (int m = 0; m < 2; ++m)
                #pragma unroll
                for (int j = 0; j < 4; ++j)
                    acc[m][j] = __builtin_amdgcn_mfma_f32_16x16x32_bf16(
                        ah[m], bh[j], acc[m][j], 0, 0, 0);
            #pragma unroll
            for (int m = 0; m < 2; ++m)
                #pragma unroll
                for (int j = 0; j < 4; ++j)
                    acc[m][j] = __builtin_amdgcn_mfma_f32_16x16x32_bf16(
                        ah[m], bl[j], acc[m][j], 0, 0, 0);
            #pragma unroll
            for (int m = 0; m < 2; ++m)
                #pragma unroll
                for (int j = 0; j < 4; ++j)
                    acc[m][j] = __builtin_amdgcn_mfma_f32_16x16x32_bf16(
                        al[m], bh[j], acc[m][j], 0, 0, 0);
        }
        __syncthreads();
    }

    // ---- fused head ----
    for (int t = tid; t < TBM * 2; t += 512) ((float*)hacc)[t] = 0.f;
    __syncthreads();

    int mids[2][4];
    #pragma unroll
    for (int m = 0; m < 2; ++m)
        #pragma unroll
        for (int rr = 0; rr < 4; ++rr)
            mids[m][rr] = model_ids[row0 + wm * 32 + m * 16 + l4 * 4 + rr];

    float s[2][4][2] = {};
    #pragma unroll
    for (int j = 0; j < 4; ++j) {
        int col = wn * 64 + j * 16 + l15;
        if (col < N) {
            float w0 = cls_W[col], w1 = cls_W[N + col], bv = bias[col];
            #pragma unroll
            for (int m = 0; m < 2; ++m) {
                #pragma unroll
                for (int rr = 0; rr < 4; ++rr) {
                    float p  = x2f[(size_t)mids[m][rr] * N + col];
                    float pv = (acc[m][j][rr] + bv) * p;
                    s[m][rr][0] += pv * w0;
                    s[m][rr][1] += pv * w1;
                }
            }
        }
    }
    #pragma unroll
    for (int off = 1; off < 16; off <<= 1)
        #pragma unroll
        for (int m = 0; m < 2; ++m)
            #pragma unroll
            for (int rr = 0; rr < 4; ++rr) {
                s[m][rr][0] += __shfl_xor(s[m][rr][0], off);
                s[m][rr][1] += __shfl_xor(s[m][rr][1], off);
            }
    if (l15 == 0) {
        #pragma unroll
        for (int m = 0; m < 2; ++m)
            #pragma unroll
            for (int rr = 0; rr < 4; ++rr) {
                int lr = wm * 32 + m * 16 + l4 * 4 + rr;
                atomicAdd(&hacc[lr][0], s[m][rr][0]);
                atomicAdd(&hacc[lr][1], s[m][rr][1]);
            }
    }
    __syncthreads();
    for (int t = tid; t < TBM; t += 512) {
        out[(size_t)(row0 + t) * 2 + 0] = hacc[t][0] + cls_b[0];
        out[(size_t)(row0 + t) * 2 + 1] = hacc[t][1] + cls_b[1];
    }
}

// ---------------- fp32 -> bf16 hi/lo planes (weights only) ----------------
struct Seg  { const float* src; u16* hi; u16* lo; int n4; };
struct Segs { Seg s[6]; };

__global__ __launch_bounds__(256) void conv_multi(Segs segs, int total4)
{
    int i = blockIdx.x * blockDim.x + threadIdx.x;
    const int stride = gridDim.x * blockDim.x;
    for (; i < total4; i += stride) {
        int k = i, si = 0;
        while (k >= segs.s[si].n4) { k -= segs.s[si].n4; ++si; }
        float4 v = reinterpret_cast<const float4*>(segs.s[si].src)[k];
        float f[4] = {v.x, v.y, v.z, v.w};
        ushort4 h, l;
        u16* hp = (u16*)&h; u16* lp = (u16*)&l;
        #pragma unroll
        for (int c = 0; c < 4; ++c) {
            u16 hh = f2bf(f[c]);
            hp[c] = hh; lp[c] = f2bf(f[c] - bf2f(hh));
        }
        reinterpret_cast<ushort4*>(segs.s[si].hi)[k] = h;
        reinterpret_cast<ushort4*>(segs.s[si].lo)[k] = l;
    }
}

// ---------------- CSR build ----------------
__global__ void hist_kernel(const int* __restrict__ dst, int* __restrict__ hist, int E)
{
    int e = blockIdx.x * blockDim.x + threadIdx.x;
    if (e < E) atomicAdd(&hist[dst[e]], 1);
}

__global__ __launch_bounds__(1024) void scan_kernel(
    const int* __restrict__ hist, int* __restrict__ row_ptr,
    float* __restrict__ invdeg, int E)
{
    __shared__ int s[1024];
    const int t = threadIdx.x;
    int4 c = reinterpret_cast<const int4*>(hist)[t];
    int local = c.x + c.y + c.z + c.w;
    s[t] = local;
    __syncthreads();
    for (int off = 1; off < 1024; off <<= 1) {
        int v = (t >= off) ? s[t - off] : 0;
        __syncthreads();
        s[t] += v;
        __syncthreads();
    }
    int base = s[t] - local;
    row_ptr[4 * t + 0] = base;
    row_ptr[4 * t + 1] = base + c.x;
    row_ptr[4 * t + 2] = base + c.x + c.y;
    row_ptr[4 * t + 3] = base + c.x + c.y + c.z;
    if (t == 1023) row_ptr[4096] = E;
    invdeg[4 * t + 0] = 1.0f / fmaxf((float)c.x, 1.0f);
    invdeg[4 * t + 1] = 1.0f / fmaxf((float)c.y, 1.0f);
    invdeg[4 * t + 2] = 1.0f / fmaxf((float)c.z, 1.0f);
    invdeg[4 * t + 3] = 1.0f / fmaxf((float)c.w, 1.0f);
}

__global__ void scatter_kernel(
    const int* __restrict__ src, const int* __restrict__ dst,
    const int* __restrict__ row_ptr, int* __restrict__ cursor,
    int* __restrict__ csr, int E)
{
    int e = blockIdx.x * blockDim.x + threadIdx.x;
    if (e >= E) return;
    int d = dst[e];
    int pos = atomicAdd(&cursor[d], 1);
    csr[row_ptr[d] + pos] = src[e];
}

__device__ __forceinline__ void add4(float4& a, const float4 b) {
    a.x += b.x; a.y += b.y; a.z += b.z; a.w += b.w;
}

// one wave per node: agg[i] = invdeg[i] * sum_{s in N(i)} x[s]  (fp32 out)
__global__ __launch_bounds__(256) void node_agg(
    const int* __restrict__ row_ptr, const int* __restrict__ csr,
    const float* __restrict__ invdeg,
    const float* __restrict__ x, float* __restrict__ agg, int D)
{
    const int wave = threadIdx.x >> 6;
    const int lane = threadIdx.x & 63;
    const int node = blockIdx.x * 4 + wave;
    const int beg = row_ptr[node], end = row_ptr[node + 1];
    const bool act = lane < (D >> 2);
    const int fo = lane * 4;

    float4 s0 = {0,0,0,0}, s1 = {0,0,0,0}, s2 = {0,0,0,0}, s3 = {0,0,0,0};
    int j = beg;
    for (; j + 3 < end; j += 4) {
        int n0 = csr[j], n1 = csr[j + 1], n2 = csr[j + 2], n3 = csr[j + 3];
        if (act) {
            add4(s0, *reinterpret_cast<const float4*>(&x[(size_t)n0 * D + fo]));
            add4(s1, *reinterpret_cast<const float4*>(&x[(size_t)n1 * D + fo]));
            add4(s2, *reinterpret_cast<const float4*>(&x[(size_t)n2 * D + fo]));
            add4(s3, *reinterpret_cast<const float4*>(&x[(size_t)n3 * D + fo]));
        }
    }
    for (; j < end; ++j) {
        int n = csr[j];
        if (act) add4(s0, *reinterpret_cast<const float4*>(&x[(size_t)n * D + fo]));
    }
    if (act) {
        const float inv = invdeg[node];
        float4 r;
        r.x = (s0.x + s1.x + s2.x + s3.x) * inv;
        r.y = (s0.y + s1.y + s2.y + s3.y) * inv;
        r.z = (s0.z + s1.z + s2.z + s3.z) * inv;
        r.w = (s0.w + s1.w + s2.w + s3.w) * inv;
        *reinterpret_cast<float4*>(&agg[(size_t)node * D + fo]) = r;
    }
}

extern "C" void kernel_launch(void* const* d_in, const int* in_sizes, int n_in,
                              void* d_out, int out_size, void* d_ws, size_t ws_size,
                              hipStream_t stream)
{
    const float* P_weight     = (const float*)d_in[0];
    const float* model_proj_W = (const float*)d_in[1];
    const float* model_proj_b = (const float*)d_in[2];
    const float* sage1_Wl     = (const float*)d_in[3];
    const float* sage1_bl     = (const float*)d_in[4];
    const float* sage1_Wr     = (const float*)d_in[5];
    const float* sage2_Wl     = (const float*)d_in[6];
    const float* sage2_bl     = (const float*)d_in[7];
    const float* sage2_Wr     = (const float*)d_in[8];
    const float* Q_weight     = (const float*)d_in[9];
    const float* text_proj_W  = (const float*)d_in[10];
    const float* text_proj_b  = (const float*)d_in[11];
    const float* cls_W        = (const float*)d_in[12];
    const float* cls_b        = (const float*)d_in[13];
    const int*   edge_index   = (const int*)d_in[14];
    const int*   model_ids    = (const int*)d_in[15];
    const int*   prompt_ids   = (const int*)d_in[16];

    const int E = in_sizes[14] / 2;
    const int B = in_sizes[15];
    const int* srcE = edge_index;
    const int* dstE = edge_index + E;

    // ---- workspace layout ----
    const size_t nX0 = (size_t)NTRAIN * D0;   // 950272
    const size_t nH1 = (size_t)NTRAIN * HID;  // 1048576
    const size_t nWp = (size_t)D0 * MED;      // 237568
    const size_t nWs = (size_t)HID * D0;      // 59392 (all four sage weights)
    const size_t nWt = (size_t)D0 * TDIM;     // 178176
    const size_t nWAll = nWp + 4 * nWs + nWt; // 653312

    float* fp  = (float*)d_ws;
    float* x0f = fp;  fp += nX0;
    float* h1f = fp;  fp += nH1;
    float* x2f = fp;  fp += nX0;
    float* agf = fp;  fp += nH1;
    u16* sp  = (u16*)fp;
    u16* x0h = sp;    sp += nX0;
    u16* x0l = sp;    sp += nX0;
    u16* h1h = sp;    sp += nH1;
    u16* h1l = sp;    sp += nH1;
    u16* Wh  = sp;    sp += nWAll;
    u16* Wl  = sp;    sp += nWAll;
    int* ib  = (int*)sp;
    int*   hist    = ib;
    int*   cursor  = ib + 4096;
    int*   row_ptr = ib + 8192;              // 4097, padded
    float* invdeg  = (float*)(ib + 12304);
    int*   csr     = ib + 16400;

    u16 *Wph = Wh,            *Wpl = Wl;
    u16 *W1lh = Wh + nWp,     *W1ll = Wl + nWp;
    u16 *W1rh = W1lh + nWs,   *W1rl = W1ll + nWs;
    u16 *W2lh = W1rh + nWs,   *W2ll = W1rl + nWs;
    u16 *W2rh = W2lh + nWs,   *W2rl = W2ll + nWs;
    u16 *Wth  = W2rh + nWs,   *Wtl  = W2rl + nWs;

    dim3 blk(256);

    hipMemsetAsync(ib, 0, 8192 * sizeof(int), stream);

    // CSR build
    hist_kernel<<<(E + 255) / 256, blk, 0, stream>>>(dstE, hist, E);
    scan_kernel<<<1, 1024, 0, stream>>>(hist, row_ptr, invdeg, E);
    scatter_kernel<<<(E + 255) / 256, blk, 0, stream>>>(srcE, dstE, row_ptr, cursor, csr, E);

    // weights -> hi/lo planes
    Segs segs;
    segs.s[0] = {model_proj_W, Wph,  Wpl,  (int)(nWp / 4)};
    segs.s[1] = {sage1_Wl,     W1lh, W1ll, (int)(nWs / 4)};
    segs.s[2] = {sage1_Wr,     W1rh, W1rl, (int)(nWs / 4)};
    segs.s[3] = {sage2_Wl,     W2lh, W2ll, (int)(nWs / 4)};
    segs.s[4] = {sage2_Wr,     W2rh, W2rl, (int)(nWs / 4)};
    segs.s[5] = {text_proj_W,  Wth,  Wtl,  (int)(nWt / 4)};
    conv_multi<<<640, blk, 0, stream>>>(segs, (int)(nWAll / 4));

    // x0 = P[:4096] @ Wp^T + b    (emits x0 planes)
    gemm_node<0, 1><<<dim3(2, NTRAIN / 32), blk, 0, stream>>>(
        P_weight, (const short*)Wph, (const short*)Wpl,
        nullptr, nullptr, nullptr, nullptr,
        model_proj_b, x0f, x0h, x0l, NTRAIN, D0, MED);

    // layer-1 aggregation
    node_agg<<<NTRAIN / 4, blk, 0, stream>>>(row_ptr, csr, invdeg, x0f, agf, D0);

    // h1 = relu(agg @ W1l^T + b1 + x0 @ W1r^T)   (emits h1 planes)
    gemm_node<1, 1><<<dim3(2, NTRAIN / 32), blk, 0, stream>>>(
        agf, (const short*)W1lh, (const short*)W1ll,
        (const short*)x0h, (const short*)x0l,
        (const short*)W1rh, (const short*)W1rl,
        sage1_bl, h1f, h1h, h1l, NTRAIN, HID, D0);

    // layer-2 aggregation
    node_agg<<<NTRAIN / 4, blk, 0, stream>>>(row_ptr, csr, invdeg, h1f, agf, HID);

    // x2 = agg @ W2l^T + b2 + h1 @ W2r^T
    gemm_node<0, 0><<<dim3(2, NTRAIN / 32), blk, 0, stream>>>(
        agf, (const short*)W2lh, (const short*)W2ll,
        (const short*)h1h, (const short*)h1l,
        (const short*)W2rh, (const short*)W2rl,
        sage2_bl, x2f, nullptr, nullptr, NTRAIN, D0, HID);

    // fused q-GEMM + head -> d_out
    gemm_q_head<<<B / 64, dim3(512), 0, stream>>>(
        Q_weight, prompt_ids, (const short*)Wth, (const short*)Wtl,
        text_proj_b, x2f, model_ids, cls_W, cls_b, (float*)d_out);
}